// Round 15
// baseline (42.773 us; speedup 1.0000x reference)
//
#include <hip/hip_runtime.h>
#include <math.h>

// InfiniteContextAttention — causal mask reaches only keys 0..15 (= compressed_k/v[:,:, :16]).
// Pipeline: q = hidden @ Wq^T -> 16-key causal attention -> out = attn @ Wo^T.
//
// v15 = v7 (37.4us, proven) with EXACTLY ONE change: fp32->bf16 uses TRUNCATION
// (high 16 bits) via v_perm_b32 (__builtin_amdgcn_perm — compiler-visible, no
// inline asm). 1 instr / 2 elems: K-loop B-convert ~44 -> 4 VALU ops/step.
// r13/r14 lesson: cvt_pk via builtin-f22bf162 AND via inline asm BOTH lose ~4.5us
// (schedule perturbation: NaN-branchy lowering / asm opacity). Truncation is the
// only encoding with both minimal ops AND clean compiler-visible dataflow.
// Numerics: truncation doubles bf16 quantization vs RNE -> absmax ~0.06 < 0.1056.

#define HID 4096
#define NROW 32
#define NSLICE 8
#define KSL 512
#define NSTEP 16
#define PART_STRIDE (NROW * HID)  // 131072 floats per slice

typedef __attribute__((ext_vector_type(8))) short short8;
typedef __attribute__((ext_vector_type(4))) float f32x4;

// one v_perm_b32: dst[15:0] = lo[31:16], dst[31:16] = hi[31:16]  (bf16 truncate-pack)
__device__ __forceinline__ unsigned pack_bf16_trunc(float lo, float hi) {
    return __builtin_amdgcn_perm(__builtin_bit_cast(unsigned, hi),
                                 __builtin_bit_cast(unsigned, lo),
                                 0x07060302u);
}

__device__ __forceinline__ unsigned long long cvt4(float4 v) {
    return (unsigned long long)pack_bf16_trunc(v.x, v.y)
         | ((unsigned long long)pack_bf16_trunc(v.z, v.w) << 32);
}

__device__ __forceinline__ short8 cvt8(float4 a, float4 b) {
    union { short8 s; unsigned u[4]; } r;
    r.u[0] = pack_bf16_trunc(a.x, a.y);
    r.u[1] = pack_bf16_trunc(a.z, a.w);
    r.u[2] = pack_bf16_trunc(b.x, b.y);
    r.u[3] = pack_bf16_trunc(b.z, b.w);
    return r.s;
}

__global__ __launch_bounds__(256, 2)
void gemm_mfma(const float* __restrict__ A,   // [32][4096] fp32
               const float* __restrict__ W,   // [4096][4096] fp32
               float* __restrict__ P)         // [8][32][4096] fp32 partials
{
    __shared__ short As[NROW * KSL];  // 32 KB bf16, XOR-swizzled (T2)
    const int tid  = threadIdx.x;
    const int lane = tid & 63;
    const int wv   = tid >> 6;            // wave 0..3 -> 16-col tile
    const int cg   = blockIdx.x & 63;     // column group (64 cols)
    const int sl   = blockIdx.x >> 6;     // K-slice 0..7
    const int ks   = sl * KSL;

    // ---- stage A slice (fp32 -> bf16 truncate, swizzled) ----
    {
        const int r  = tid >> 3;          // row 0..31
        const int c8 = tid & 7;           // float4 column subgroup
        const float* src = A + (size_t)r * HID + ks + c8 * 4;
        char* lb = (char*)As + r * (KSL * 2);
        const int rx = (r & 7) << 4;
#pragma unroll
        for (int i = 0; i < 16; ++i) {
            float4 v = *(const float4*)(src + i * 32);
            int byte = ((c8 + 8 * i) * 8) ^ rx;
            *(unsigned long long*)(lb + byte) = cvt4(v);
        }
    }
    __syncthreads();  // the only barrier: LDS written once

    const int l15 = lane & 15, lq = lane >> 4, l7 = lane & 7;
    const int jcol = cg * 64 + wv * 16 + l15;
    const float* wp = W + (size_t)jcol * HID + ks + lq * 8;
    const char* lA0 = (const char*)As + l15 * (KSL * 2);
    const char* lA1 = (const char*)As + (16 + l15) * (KSL * 2);
    const int rswz = l7 << 4;

    f32x4 acc0 = {0.f, 0.f, 0.f, 0.f}, acc1 = {0.f, 0.f, 0.f, 0.f};

    // depth-3 rolling W prefetch (r7/r11: depth is a null knob; keep v7's form)
    float4 w0a = *(const float4*)(wp);
    float4 w0b = *(const float4*)(wp + 4);
    float4 w1a = *(const float4*)(wp + 32);
    float4 w1b = *(const float4*)(wp + 36);
    float4 w2a = *(const float4*)(wp + 64);
    float4 w2b = *(const float4*)(wp + 68);

#pragma unroll
    for (int kk = 0; kk < NSTEP; ++kk) {
        float4 nA = {}, nB = {};
        if (kk < NSTEP - 3) {
            nA = *(const float4*)(wp + (kk + 3) * 32);
            nB = *(const float4*)(wp + (kk + 3) * 32 + 4);
        }
        const int byte = ((kk * 64) + (lq * 16)) ^ rswz;
        short8 a0 = *(const short8*)(lA0 + byte);
        short8 a1 = *(const short8*)(lA1 + byte);
        short8 b = cvt8(w0a, w0b);   // 4x v_perm_b32 (was ~44 VALU ops)
        acc0 = __builtin_amdgcn_mfma_f32_16x16x32_bf16(a0, b, acc0, 0, 0, 0);
        acc1 = __builtin_amdgcn_mfma_f32_16x16x32_bf16(a1, b, acc1, 0, 0, 0);
        w0a = w1a; w0b = w1b; w1a = w2a; w1b = w2b; w2a = nA; w2b = nB;
    }

    // ---- epilogue: C/D layout col=lane&15, row=(lane>>4)*4+reg (m89-verified) ----
    float* pout = P + (size_t)sl * PART_STRIDE + jcol;
#pragma unroll
    for (int rr = 0; rr < 4; ++rr) {
        pout[(size_t)(lq * 4 + rr) * HID]        = acc0[rr];
        pout[(size_t)(16 + lq * 4 + rr) * HID]   = acc1[rr];
    }
}

// One wave per (b,h,i): fuses the 8-slice q-reduction with 16-key causal attention.
__global__ __launch_bounds__(256)
void attn16_kernel(const float* __restrict__ P,   // q partials [8][32][4096]
                   const float* __restrict__ ck,
                   const float* __restrict__ cv,
                   float* __restrict__ o)          // [32][4096]
{
    const int lane = threadIdx.x & 63;
    const int g = blockIdx.x * 4 + (threadIdx.x >> 6);  // 0..1023
    const int b = g >> 9;
    const int h = (g >> 4) & 31;
    const int i = g & 15;

    const size_t qoff = ((size_t)(b * 16 + i)) * HID + h * 128 + 2 * lane;
    float2 q2 = {0.f, 0.f};
#pragma unroll
    for (int s = 0; s < NSLICE; ++s) {
        float2 p = *(const float2*)(P + (size_t)s * PART_STRIDE + qoff);
        q2.x += p.x; q2.y += p.y;
    }
    const size_t kvoff = ((size_t)(b * 32 + h)) * 2048 * 128 + 2 * lane;
    const float* kp = ck + kvoff;
    const float* vp = cv + kvoff;

    float e[16];
#pragma unroll
    for (int s = 0; s < 16; ++s) {
        float2 k2 = *(const float2*)(kp + (size_t)s * 128);
        float p = q2.x * k2.x + q2.y * k2.y;
#pragma unroll
        for (int m = 32; m >= 1; m >>= 1) p += __shfl_xor(p, m, 64);
        e[s] = (s <= i) ? p * 0.08838834764831845f : -3.4e38f;  // i wave-uniform
    }
    float mx = e[0];
#pragma unroll
    for (int s = 1; s < 16; ++s) mx = fmaxf(mx, e[s]);
    float den = 0.f;
#pragma unroll
    for (int s = 0; s < 16; ++s) { e[s] = __expf(e[s] - mx); den += e[s]; }
    const float inv = 1.0f / den;

    float ox = 0.f, oy = 0.f;
#pragma unroll
    for (int s = 0; s < 16; ++s) {
        float2 v2 = *(const float2*)(vp + (size_t)s * 128);
        ox += e[s] * v2.x;
        oy += e[s] * v2.y;
    }
    float2 res; res.x = ox * inv; res.y = oy * inv;
    *(float2*)(o + qoff) = res;
}

// out[i] = sum over 8 slices of P[s][i]; 32768 float4s.
__global__ __launch_bounds__(256)
void reduce8_kernel(const float* __restrict__ P, float* __restrict__ out)
{
    const int idx = blockIdx.x * 256 + threadIdx.x;  // float4 index
    const float4* p4 = (const float4*)P;
    float4 s = p4[idx];
#pragma unroll
    for (int t = 1; t < NSLICE; ++t) {
        float4 v = p4[idx + t * (PART_STRIDE / 4)];
        s.x += v.x; s.y += v.y; s.z += v.z; s.w += v.w;
    }
    ((float4*)out)[idx] = s;
}

extern "C" void kernel_launch(void* const* d_in, const int* in_sizes, int n_in,
                              void* d_out, int out_size, void* d_ws, size_t ws_size,
                              hipStream_t stream) {
    const float* hidden = (const float*)d_in[0];  // [2][16][4096]
    const float* ck     = (const float*)d_in[3];  // [2][32][2048][128]
    const float* cv     = (const float*)d_in[4];
    const float* Wq     = (const float*)d_in[5];  // [4096][4096]
    const float* Wo     = (const float*)d_in[8];
    float* out  = (float*)d_out;                  // [2][16][4096]
    float* part = (float*)d_ws;                   // [8][32][4096] = 4 MB
    float* abuf = part + NSLICE * PART_STRIDE;    // [32][4096] attn output

    hipLaunchKernelGGL(gemm_mfma,     dim3(512), dim3(256), 0, stream, hidden, Wq, part);
    hipLaunchKernelGGL(attn16_kernel, dim3(256), dim3(256), 0, stream, part, ck, cv, abuf);
    hipLaunchKernelGGL(gemm_mfma,     dim3(512), dim3(256), 0, stream, abuf, Wo, part);
    hipLaunchKernelGGL(reduce8_kernel,dim3(128), dim3(256), 0, stream, part, out);
}

// Round 17
// 40.551 us; speedup vs baseline: 1.0548x; 1.0548x over previous
//
#include <hip/hip_runtime.h>
#include <math.h>

// InfiniteContextAttention — causal mask reaches only keys 0..15 (= compressed_k/v[:,:, :16]).
// Pipeline: q = hidden @ Wq^T -> 16-key causal attention -> out = attn @ Wo^T.
//
// v17 = v16 with the staging bug fixed (8 iters, full 128 granules/row; v16's
// 4 iters left half the A-tile unwritten -> NaN). The experiment is unchanged:
// 8 waves/block via intra-block 2-way K-split (waves 0-3: K[0,256), waves 4-7:
// K[256,512)). Same grid/bytes/work as v7; waves/SIMD 2 -> 4.
// Rationale: r13/r14/r15 conversion triplet shows the K-loop is dependency-
// exposed at 2 waves/SIMD; the clean cure is TLP.

#define HID 4096
#define NROW 32
#define NSLICE 8
#define KSL 512
#define KHALF 256
#define NSTEP8 8                  // MFMA K-steps per wave (K=256 / 32)
#define PART_STRIDE (NROW * HID)  // 131072 floats per slice

typedef __attribute__((ext_vector_type(8))) short short8;
typedef __attribute__((ext_vector_type(4))) float f32x4;

__device__ __forceinline__ unsigned short bf16_rne(float x) {
    union { float f; unsigned u; } c; c.f = x;
    unsigned u = c.u;
    return (unsigned short)((u + 0x7fffu + ((u >> 16) & 1u)) >> 16);
}

__device__ __forceinline__ unsigned long long pk4(float4 v) {
    return (unsigned long long)bf16_rne(v.x)
         | ((unsigned long long)bf16_rne(v.y) << 16)
         | ((unsigned long long)bf16_rne(v.z) << 32)
         | ((unsigned long long)bf16_rne(v.w) << 48);
}

__global__ __launch_bounds__(512, 4)
void gemm_mfma(const float* __restrict__ A,   // [32][4096] fp32
               const float* __restrict__ W,   // [4096][4096] fp32
               float* __restrict__ P)         // [8][32][4096] fp32 partials
{
    __shared__ short As[NROW * KSL];  // 32 KB bf16, XOR-swizzled; reused as epilogue scratch
    const int tid  = threadIdx.x;
    const int lane = tid & 63;
    const int wv   = tid >> 6;            // wave 0..7
    const int ct   = wv & 3;              // col-tile (16 cols) within block
    const int kh   = wv >> 2;             // K-half 0/1
    const int cg   = blockIdx.x & 63;     // column group (64 cols)
    const int sl   = blockIdx.x >> 6;     // K-slice 0..7
    const int ks   = sl * KSL;

    // ---- stage A slice (fp32 -> bf16 hand-RNE, swizzled): 512 thr x 8 iters ----
    // FIX vs v16: 8 iterations -> slots c+16*i for i in [0,8) cover all 128
    // granules per row (v16's 4 iters staged only half the tile -> NaN).
    {
        const int r = tid >> 4;           // row 0..31, 16 threads per row
        const int c = tid & 15;           // granule subgroup within row
        const float* src = A + (size_t)r * HID + ks + c * 4;
        char* lb = (char*)As + r * (KSL * 2);
        const int rx = (r & 7) << 4;
#pragma unroll
        for (int i = 0; i < 8; ++i) {
            float4 v = *(const float4*)(src + i * 64);
            int byte = ((c + 16 * i) * 8) ^ rx;   // same layout as v7
            *(unsigned long long*)(lb + byte) = pk4(v);
        }
    }
    __syncthreads();

    const int l15 = lane & 15, lq = lane >> 4;
    const int jcol = cg * 64 + ct * 16 + l15;
    const float* wp = W + (size_t)jcol * HID + ks + kh * KHALF + lq * 8;
    const char* lA0 = (const char*)As + l15 * (KSL * 2);
    const char* lA1 = (const char*)As + (16 + l15) * (KSL * 2);
    const int rswz = (l15 & 7) << 4;

    f32x4 acc0 = {0.f, 0.f, 0.f, 0.f}, acc1 = {0.f, 0.f, 0.f, 0.f};

    // depth-3 rolling W prefetch over 8 steps (v7's proven form)
    float4 w0a = *(const float4*)(wp);
    float4 w0b = *(const float4*)(wp + 4);
    float4 w1a = *(const float4*)(wp + 32);
    float4 w1b = *(const float4*)(wp + 36);
    float4 w2a = *(const float4*)(wp + 64);
    float4 w2b = *(const float4*)(wp + 68);

#pragma unroll
    for (int kk = 0; kk < NSTEP8; ++kk) {
        float4 nA = {}, nB = {};
        if (kk < NSTEP8 - 3) {
            nA = *(const float4*)(wp + (kk + 3) * 32);
            nB = *(const float4*)(wp + (kk + 3) * 32 + 4);
        }
        const int byte = (((kh * 8 + kk) * 64) + (lq * 16)) ^ rswz;
        short8 a0 = *(const short8*)(lA0 + byte);
        short8 a1 = *(const short8*)(lA1 + byte);
        short8 b;
        b[0] = (short)bf16_rne(w0a.x); b[1] = (short)bf16_rne(w0a.y);
        b[2] = (short)bf16_rne(w0a.z); b[3] = (short)bf16_rne(w0a.w);
        b[4] = (short)bf16_rne(w0b.x); b[5] = (short)bf16_rne(w0b.y);
        b[6] = (short)bf16_rne(w0b.z); b[7] = (short)bf16_rne(w0b.w);
        acc0 = __builtin_amdgcn_mfma_f32_16x16x32_bf16(a0, b, acc0, 0, 0, 0);
        acc1 = __builtin_amdgcn_mfma_f32_16x16x32_bf16(a1, b, acc1, 0, 0, 0);
        w0a = w1a; w0b = w1b; w1a = w2a; w1b = w2b; w2a = nA; w2b = nB;
    }

    // ---- epilogue: 2-way K-half reduce via LDS scratch, then store (m89 layout) ----
    __syncthreads();                      // all As reads done; safe to overlay
    float* red = (float*)As;              // 4 tiles x 32 rows x 16 cols = 8 KB
    if (kh == 1) {
        float* rb = red + ct * 512;
#pragma unroll
        for (int rr = 0; rr < 4; ++rr) {
            rb[(lq * 4 + rr) * 16 + l15]      = acc0[rr];
            rb[(16 + lq * 4 + rr) * 16 + l15] = acc1[rr];
        }
    }
    __syncthreads();
    if (kh == 0) {
        const float* rb = red + ct * 512;
        float* pout = P + (size_t)sl * PART_STRIDE + jcol;
#pragma unroll
        for (int rr = 0; rr < 4; ++rr) {
            pout[(size_t)(lq * 4 + rr) * HID]      = acc0[rr] + rb[(lq * 4 + rr) * 16 + l15];
            pout[(size_t)(16 + lq * 4 + rr) * HID] = acc1[rr] + rb[(16 + lq * 4 + rr) * 16 + l15];
        }
    }
}

// One wave per (b,h,i): fuses the 8-slice q-reduction with 16-key causal attention.
__global__ __launch_bounds__(256)
void attn16_kernel(const float* __restrict__ P,   // q partials [8][32][4096]
                   const float* __restrict__ ck,
                   const float* __restrict__ cv,
                   float* __restrict__ o)          // [32][4096]
{
    const int lane = threadIdx.x & 63;
    const int g = blockIdx.x * 4 + (threadIdx.x >> 6);  // 0..1023
    const int b = g >> 9;
    const int h = (g >> 4) & 31;
    const int i = g & 15;

    const size_t qoff = ((size_t)(b * 16 + i)) * HID + h * 128 + 2 * lane;
    float2 q2 = {0.f, 0.f};
#pragma unroll
    for (int s = 0; s < NSLICE; ++s) {
        float2 p = *(const float2*)(P + (size_t)s * PART_STRIDE + qoff);
        q2.x += p.x; q2.y += p.y;
    }
    const size_t kvoff = ((size_t)(b * 32 + h)) * 2048 * 128 + 2 * lane;
    const float* kp = ck + kvoff;
    const float* vp = cv + kvoff;

    float e[16];
#pragma unroll
    for (int s = 0; s < 16; ++s) {
        float2 k2 = *(const float2*)(kp + (size_t)s * 128);
        float p = q2.x * k2.x + q2.y * k2.y;
#pragma unroll
        for (int m = 32; m >= 1; m >>= 1) p += __shfl_xor(p, m, 64);
        e[s] = (s <= i) ? p * 0.08838834764831845f : -3.4e38f;  // i wave-uniform
    }
    float mx = e[0];
#pragma unroll
    for (int s = 1; s < 16; ++s) mx = fmaxf(mx, e[s]);
    float den = 0.f;
#pragma unroll
    for (int s = 0; s < 16; ++s) { e[s] = __expf(e[s] - mx); den += e[s]; }
    const float inv = 1.0f / den;

    float ox = 0.f, oy = 0.f;
#pragma unroll
    for (int s = 0; s < 16; ++s) {
        float2 v2 = *(const float2*)(vp + (size_t)s * 128);
        ox += e[s] * v2.x;
        oy += e[s] * v2.y;
    }
    float2 res; res.x = ox * inv; res.y = oy * inv;
    *(float2*)(o + qoff) = res;
}

// out[i] = sum over 8 slices of P[s][i]; 32768 float4s.
__global__ __launch_bounds__(256)
void reduce8_kernel(const float* __restrict__ P, float* __restrict__ out)
{
    const int idx = blockIdx.x * 256 + threadIdx.x;  // float4 index
    const float4* p4 = (const float4*)P;
    float4 s = p4[idx];
#pragma unroll
    for (int t = 1; t < NSLICE; ++t) {
        float4 v = p4[idx + t * (PART_STRIDE / 4)];
        s.x += v.x; s.y += v.y; s.z += v.z; s.w += v.w;
    }
    ((float4*)out)[idx] = s;
}

extern "C" void kernel_launch(void* const* d_in, const int* in_sizes, int n_in,
                              void* d_out, int out_size, void* d_ws, size_t ws_size,
                              hipStream_t stream) {
    const float* hidden = (const float*)d_in[0];  // [2][16][4096]
    const float* ck     = (const float*)d_in[3];  // [2][32][2048][128]
    const float* cv     = (const float*)d_in[4];
    const float* Wq     = (const float*)d_in[5];  // [4096][4096]
    const float* Wo     = (const float*)d_in[8];
    float* out  = (float*)d_out;                  // [2][16][4096]
    float* part = (float*)d_ws;                   // [8][32][4096] = 4 MB
    float* abuf = part + NSLICE * PART_STRIDE;    // [32][4096] attn output

    hipLaunchKernelGGL(gemm_mfma,     dim3(512), dim3(512), 0, stream, hidden, Wq, part);
    hipLaunchKernelGGL(attn16_kernel, dim3(256), dim3(256), 0, stream, part, ck, cv, abuf);
    hipLaunchKernelGGL(gemm_mfma,     dim3(512), dim3(512), 0, stream, abuf, Wo, part);
    hipLaunchKernelGGL(reduce8_kernel,dim3(128), dim3(256), 0, stream, part, out);
}

// Round 18
// 37.413 us; speedup vs baseline: 1.1433x; 1.0839x over previous
//
#include <hip/hip_runtime.h>
#include <math.h>

// InfiniteContextAttention — causal mask reaches only keys 0..15 (= compressed_k/v[:,:, :16]).
// Pipeline: q = hidden @ Wq^T -> 16-key causal attention -> out = attn @ Wo^T.
//
// v18 = v7 EXACTLY (37.4us, best, 3x reproduced). Restoration after the axis
// sweep: prefetch depth (1/3/32) null; prologue placement null; W-via-LDS -70%;
// conversion encodings (cvt builtin / asm cvt_pk / perm-truncate) all -12%;
// clean TLP 2->4 waves/SIMD -8%; coop fusion -5.5x; ticket fan-in -2.6x.
// Structure: 512 blocks x 256 thr; block = 64 cols x K-slice 512; A staged once
// into XOR-swizzled bf16 LDS (one barrier); W streamed global->reg (depth-3,
// hand-RNE convert); K-split partials [8][32][4096]; attn fuses q-reduce;
// reduce8 sums out partials.

#define HID 4096
#define NROW 32
#define NSLICE 8
#define KSL 512
#define NSTEP 16
#define PART_STRIDE (NROW * HID)  // 131072 floats per slice

typedef __attribute__((ext_vector_type(8))) short short8;
typedef __attribute__((ext_vector_type(4))) float f32x4;

__device__ __forceinline__ unsigned short bf16_rne(float x) {
    union { float f; unsigned u; } c; c.f = x;
    unsigned u = c.u;
    return (unsigned short)((u + 0x7fffu + ((u >> 16) & 1u)) >> 16);
}

__global__ __launch_bounds__(256, 2)
void gemm_mfma(const float* __restrict__ A,   // [32][4096] fp32
               const float* __restrict__ W,   // [4096][4096] fp32
               float* __restrict__ P)         // [8][32][4096] fp32 partials
{
    __shared__ short As[NROW * KSL];  // 32 KB bf16, XOR-swizzled (T2)
    const int tid  = threadIdx.x;
    const int lane = tid & 63;
    const int wv   = tid >> 6;            // wave 0..3 -> 16-col tile
    const int cg   = blockIdx.x & 63;     // column group (64 cols)
    const int sl   = blockIdx.x >> 6;     // K-slice 0..7
    const int ks   = sl * KSL;

    // ---- stage A slice (fp32 -> bf16, swizzled), coalesced 128B-granule reads ----
    {
        const int r  = tid >> 3;          // row 0..31
        const int c8 = tid & 7;           // float4 column subgroup
        const float* src = A + (size_t)r * HID + ks + c8 * 4;
        char* lb = (char*)As + r * (KSL * 2);
        const int rx = (r & 7) << 4;
#pragma unroll
        for (int i = 0; i < 16; ++i) {
            float4 v = *(const float4*)(src + i * 32);
            unsigned long long pk =
                  (unsigned long long)bf16_rne(v.x)
                | ((unsigned long long)bf16_rne(v.y) << 16)
                | ((unsigned long long)bf16_rne(v.z) << 32)
                | ((unsigned long long)bf16_rne(v.w) << 48);
            int byte = ((c8 + 8 * i) * 8) ^ rx;
            *(unsigned long long*)(lb + byte) = pk;
        }
    }
    __syncthreads();  // the only barrier: LDS written once

    const int l15 = lane & 15, lq = lane >> 4, l7 = lane & 7;
    const int jcol = cg * 64 + wv * 16 + l15;
    const float* wp = W + (size_t)jcol * HID + ks + lq * 8;
    const char* lA0 = (const char*)As + l15 * (KSL * 2);
    const char* lA1 = (const char*)As + (16 + l15) * (KSL * 2);
    const int rswz = l7 << 4;

    f32x4 acc0 = {0.f, 0.f, 0.f, 0.f}, acc1 = {0.f, 0.f, 0.f, 0.f};

    // depth-3 rolling W prefetch
    float4 w0a = *(const float4*)(wp);
    float4 w0b = *(const float4*)(wp + 4);
    float4 w1a = *(const float4*)(wp + 32);
    float4 w1b = *(const float4*)(wp + 36);
    float4 w2a = *(const float4*)(wp + 64);
    float4 w2b = *(const float4*)(wp + 68);

#pragma unroll
    for (int kk = 0; kk < NSTEP; ++kk) {
        float4 nA = {}, nB = {};
        if (kk < NSTEP - 3) {
            nA = *(const float4*)(wp + (kk + 3) * 32);
            nB = *(const float4*)(wp + (kk + 3) * 32 + 4);
        }
        const int byte = ((kk * 64) + (lq * 16)) ^ rswz;
        short8 a0 = *(const short8*)(lA0 + byte);
        short8 a1 = *(const short8*)(lA1 + byte);
        short8 b;
        b[0] = (short)bf16_rne(w0a.x); b[1] = (short)bf16_rne(w0a.y);
        b[2] = (short)bf16_rne(w0a.z); b[3] = (short)bf16_rne(w0a.w);
        b[4] = (short)bf16_rne(w0b.x); b[5] = (short)bf16_rne(w0b.y);
        b[6] = (short)bf16_rne(w0b.z); b[7] = (short)bf16_rne(w0b.w);
        acc0 = __builtin_amdgcn_mfma_f32_16x16x32_bf16(a0, b, acc0, 0, 0, 0);
        acc1 = __builtin_amdgcn_mfma_f32_16x16x32_bf16(a1, b, acc1, 0, 0, 0);
        w0a = w1a; w0b = w1b; w1a = w2a; w1b = w2b; w2a = nA; w2b = nB;
    }

    // ---- epilogue: C/D layout col=lane&15, row=(lane>>4)*4+reg (m89-verified) ----
    float* pout = P + (size_t)sl * PART_STRIDE + jcol;
#pragma unroll
    for (int rr = 0; rr < 4; ++rr) {
        pout[(size_t)(lq * 4 + rr) * HID]        = acc0[rr];
        pout[(size_t)(16 + lq * 4 + rr) * HID]   = acc1[rr];
    }
}

// One wave per (b,h,i): fuses the 8-slice q-reduction with 16-key causal attention.
__global__ __launch_bounds__(256)
void attn16_kernel(const float* __restrict__ P,   // q partials [8][32][4096]
                   const float* __restrict__ ck,
                   const float* __restrict__ cv,
                   float* __restrict__ o)          // [32][4096]
{
    const int lane = threadIdx.x & 63;
    const int g = blockIdx.x * 4 + (threadIdx.x >> 6);  // 0..1023
    const int b = g >> 9;
    const int h = (g >> 4) & 31;
    const int i = g & 15;

    const size_t qoff = ((size_t)(b * 16 + i)) * HID + h * 128 + 2 * lane;
    float2 q2 = {0.f, 0.f};
#pragma unroll
    for (int s = 0; s < NSLICE; ++s) {
        float2 p = *(const float2*)(P + (size_t)s * PART_STRIDE + qoff);
        q2.x += p.x; q2.y += p.y;
    }
    const size_t kvoff = ((size_t)(b * 32 + h)) * 2048 * 128 + 2 * lane;
    const float* kp = ck + kvoff;
    const float* vp = cv + kvoff;

    float e[16];
#pragma unroll
    for (int s = 0; s < 16; ++s) {
        float2 k2 = *(const float2*)(kp + (size_t)s * 128);
        float p = q2.x * k2.x + q2.y * k2.y;
#pragma unroll
        for (int m = 32; m >= 1; m >>= 1) p += __shfl_xor(p, m, 64);
        e[s] = (s <= i) ? p * 0.08838834764831845f : -3.4e38f;  // i wave-uniform
    }
    float mx = e[0];
#pragma unroll
    for (int s = 1; s < 16; ++s) mx = fmaxf(mx, e[s]);
    float den = 0.f;
#pragma unroll
    for (int s = 0; s < 16; ++s) { e[s] = __expf(e[s] - mx); den += e[s]; }
    const float inv = 1.0f / den;

    float ox = 0.f, oy = 0.f;
#pragma unroll
    for (int s = 0; s < 16; ++s) {
        float2 v2 = *(const float2*)(vp + (size_t)s * 128);
        ox += e[s] * v2.x;
        oy += e[s] * v2.y;
    }
    float2 res; res.x = ox * inv; res.y = oy * inv;
    *(float2*)(o + qoff) = res;
}

// out[i] = sum over 8 slices of P[s][i]; 32768 float4s.
__global__ __launch_bounds__(256)
void reduce8_kernel(const float* __restrict__ P, float* __restrict__ out)
{
    const int idx = blockIdx.x * 256 + threadIdx.x;  // float4 index
    const float4* p4 = (const float4*)P;
    float4 s = p4[idx];
#pragma unroll
    for (int t = 1; t < NSLICE; ++t) {
        float4 v = p4[idx + t * (PART_STRIDE / 4)];
        s.x += v.x; s.y += v.y; s.z += v.z; s.w += v.w;
    }
    ((float4*)out)[idx] = s;
}

extern "C" void kernel_launch(void* const* d_in, const int* in_sizes, int n_in,
                              void* d_out, int out_size, void* d_ws, size_t ws_size,
                              hipStream_t stream) {
    const float* hidden = (const float*)d_in[0];  // [2][16][4096]
    const float* ck     = (const float*)d_in[3];  // [2][32][2048][128]
    const float* cv     = (const float*)d_in[4];
    const float* Wq     = (const float*)d_in[5];  // [4096][4096]
    const float* Wo     = (const float*)d_in[8];
    float* out  = (float*)d_out;                  // [2][16][4096]
    float* part = (float*)d_ws;                   // [8][32][4096] = 4 MB
    float* abuf = part + NSLICE * PART_STRIDE;    // [32][4096] attn output

    hipLaunchKernelGGL(gemm_mfma,     dim3(512), dim3(256), 0, stream, hidden, Wq, part);
    hipLaunchKernelGGL(attn16_kernel, dim3(256), dim3(256), 0, stream, part, ck, cv, abuf);
    hipLaunchKernelGGL(gemm_mfma,     dim3(512), dim3(256), 0, stream, abuf, Wo, part);
    hipLaunchKernelGGL(reduce8_kernel,dim3(128), dim3(256), 0, stream, part, out);
}